// Round 5
// baseline (119.007 us; speedup 1.0000x reference)
//
#include <hip/hip_runtime.h>
#include <hip/hip_bf16.h>

using bf16x8 = __attribute__((ext_vector_type(8))) short;   // 8 bf16 (16 B)
using f32x4  = __attribute__((ext_vector_type(4))) float;   // MFMA C/D frag

#define NN 1024
#define DD 128

__device__ __forceinline__ short bf16b(float f) {
    __hip_bfloat16 t = __float2bfloat16(f);
    return *(short*)&t;
}

__device__ __forceinline__ bf16x8 cvt8(const float* __restrict__ p) {
    float4 a = *(const float4*)p;
    float4 b = *(const float4*)(p + 4);
    bf16x8 r;
    r[0] = bf16b(a.x); r[1] = bf16b(a.y); r[2] = bf16b(a.z); r[3] = bf16b(a.w);
    r[4] = bf16b(b.x); r[5] = bf16b(b.y); r[6] = bf16b(b.z); r[7] = bf16b(b.w);
    return r;
}

// ---- kernel 1 (MFMA): h=S@Win^T -> M(bf16); valT=((S@Wout^T)*g)^T (bf16) ----
// grid 128 blocks (64 row-tiles x 2 batches), 4 waves.
__global__ __launch_bounds__(256) void prep_kernel(
    const float* __restrict__ states, const float* __restrict__ gates,
    const float* __restrict__ W_in, const float* __restrict__ W_out,
    __hip_bfloat16* __restrict__ M_bf, __hip_bfloat16* __restrict__ valT)
{
    __shared__ __align__(16) short s_m[16][136];    // [n_loc][d]
    __shared__ __align__(16) short s_vT[128][24];   // [d][n_loc]

    const int tid = threadIdx.x;
    const int l = tid & 63, w = tid >> 6;
    const int row_a = l & 15, kg = l >> 4;
    const int b  = blockIdx.x >> 6;
    const int n0 = (blockIdx.x & 63) * 16;
    const int colbase = w * 32;

    const float* A = states + ((size_t)b * NN + n0) * DD;

    f32x4 accH[2], accV[2];
    #pragma unroll
    for (int cp = 0; cp < 2; ++cp) {
        accH[cp] = (f32x4){0.f, 0.f, 0.f, 0.f};
        accV[cp] = (f32x4){0.f, 0.f, 0.f, 0.f};
    }

    #pragma unroll
    for (int ks = 0; ks < 4; ++ks) {
        int koff = (ks * 4 + kg) * 8;
        bf16x8 a = cvt8(A + row_a * DD + koff);
        #pragma unroll
        for (int cp = 0; cp < 2; ++cp) {
            int d = colbase + cp * 16 + row_a;
            bf16x8 b1 = cvt8(W_in  + d * DD + koff);
            bf16x8 b2 = cvt8(W_out + d * DD + koff);
            accH[cp] = __builtin_amdgcn_mfma_f32_16x16x32_bf16(a, b1, accH[cp], 0, 0, 0);
            accV[cp] = __builtin_amdgcn_mfma_f32_16x16x32_bf16(a, b2, accV[cp], 0, 0, 0);
        }
    }

    float g[4];
    #pragma unroll
    for (int q = 0; q < 4; ++q) g[q] = gates[b * NN + n0 + kg * 4 + q];

    const bool odd = (row_a & 1) != 0;
    #pragma unroll
    for (int cp = 0; cp < 2; ++cp) {
        #pragma unroll
        for (int q = 0; q < 4; ++q) {
            float hm = accH[cp][q] + 1e-8f;       // my (h+eps); col parity = lane parity
            float hp = __shfl_xor(hm, 1);         // pair partner (adjacent col/lane)
            float x = odd ? hp : hm;
            float y = odd ? hm : hp;
            float r2 = x * x + y * y;
            float out;
            if (r2 > 0.f) out = (odd ? y : x) * rsqrtf(r2);
            else          out = odd ? 0.f : 1.f;  // atan2(0,0)=0 -> cos=1,sin=0
            s_m[kg * 4 + q][colbase + cp * 16 + row_a] = bf16b(out);
            s_vT[colbase + cp * 16 + row_a][kg * 4 + q] = bf16b(accV[cp][q] * g[q]);
        }
    }
    __syncthreads();

    {   // M rows: 16B packed stores
        int r = tid >> 4, seg = tid & 15;
        bf16x8 v = *(const bf16x8*)&s_m[r][seg * 8];
        *(bf16x8*)(M_bf + ((size_t)b * NN + n0 + r) * DD + seg * 8) = v;
    }
    {   // valT[d][n0..n0+15]: 16B packed stores
        int d = tid >> 1, half = tid & 1;
        bf16x8 v = *(const bf16x8*)&s_vT[d][half * 8];
        *(bf16x8*)(valT + ((size_t)b * DD + d) * NN + n0 + half * 8) = v;
    }
}

// ---- kernel 2 (single-pass fused): per block, 16 i-rows x ALL j ----
// S=M@M^T/64 -> r_out; coupling -> LDS -> PV accumulates full field in f32 regs;
// rowsum completes in-block -> divide + store field. No partials, no 3rd kernel.
// grid (64 it x 2 b) = 128 blocks, 4 waves; wave w owns d-quarter w*32..+31.
__global__ __launch_bounds__(256) void fused_kernel(
    const __hip_bfloat16* __restrict__ M_bf,
    const __hip_bfloat16* __restrict__ valT,
    const float* __restrict__ r_acc,
    const float* __restrict__ gates,
    const float* __restrict__ cond_ptr,
    float* __restrict__ r_out,
    float* __restrict__ field)
{
    __shared__ __align__(16) short s_cpl[16][136];   // [i_loc][j_loc in chunk]
    __shared__ float s_rs[16][4];                    // [i_loc][wave]
    __shared__ float s_gate[NN];

    const int tid = threadIdx.x;
    const int l = tid & 63, w = tid >> 6;
    const int row_a = l & 15, kg = l >> 4;
    const int b  = blockIdx.x >> 6;
    const int i0 = (blockIdx.x & 63) * 16;

    const bf16x8* Mv = (const bf16x8*)(M_bf + (size_t)b * NN * DD);
    const bf16x8* Vv = (const bf16x8*)(valT + (size_t)b * DD * NN);

    // stage all gates for this batch (4 KB)
    ((float4*)s_gate)[tid] = ((const float4*)(gates + (size_t)b * NN))[tid];

    // hoist A-frags for this block's 16 i-rows (held all loop long)
    bf16x8 aF[4];
    #pragma unroll
    for (int ks = 0; ks < 4; ++ks)
        aF[ks] = Mv[(size_t)(i0 + row_a) * 16 + ks * 4 + kg];

    const float cond = fminf(fmaxf(cond_ptr[0], -5.f), 5.f);
    float g_i[4];
    #pragma unroll
    for (int q = 0; q < 4; ++q) g_i[q] = gates[(size_t)b * NN + i0 + kg * 4 + q];

    const size_t robase = (size_t)b * NN * NN;
    float rs[4] = {0.f, 0.f, 0.f, 0.f};
    f32x4 pacc[2];                                   // field[i0+kg*4+q][w*32+dt*16+row_a]
    pacc[0] = (f32x4){0.f, 0.f, 0.f, 0.f};
    pacc[1] = (f32x4){0.f, 0.f, 0.f, 0.f};

    __syncthreads();

    for (int jc = 0; jc < 8; ++jc) {
        const int j0 = jc * 128;

        // ---- S phase: this wave covers j_local = w*32 + cp*16 + row_a ----
        f32x4 acc[2];
        acc[0] = (f32x4){0.f, 0.f, 0.f, 0.f};
        acc[1] = (f32x4){0.f, 0.f, 0.f, 0.f};
        #pragma unroll
        for (int ks = 0; ks < 4; ++ks) {
            #pragma unroll
            for (int cp = 0; cp < 2; ++cp) {
                bf16x8 bb = Mv[(size_t)(j0 + w * 32 + cp * 16 + row_a) * 16 + ks * 4 + kg];
                acc[cp] = __builtin_amdgcn_mfma_f32_16x16x32_bf16(aF[ks], bb, acc[cp], 0, 0, 0);
            }
        }

        // ---- epilogue: r_out, coupling -> LDS, rowsum partials ----
        #pragma unroll
        for (int q = 0; q < 4; ++q) {
            const int i = i0 + kg * 4 + q;           // C/D row = kg*4+q [m89]
            const float gi = g_i[q];
            #pragma unroll
            for (int cp = 0; cp < 2; ++cp) {
                const int jl = w * 32 + cp * 16 + row_a;
                const int j  = j0 + jl;              // C/D col = lane&15
                float s  = acc[cp][q] * (1.f / 64.f);
                float ra = r_acc[robase + (size_t)i * NN + j];
                float rn = fminf(fmaxf(0.7f * ra + 0.3f * s, -2.f), 2.f);
                r_out[robase + (size_t)i * NN + j] = rn;
                float cpl = (i == j) ? 0.f
                            : (1.f / (1.f + __expf(-cond * rn))) * gi * s_gate[j];
                rs[q] += cpl;
                s_cpl[kg * 4 + q][jl] = bf16b(cpl);
            }
        }
        __syncthreads();

        // ---- PV: wave w owns d-quarter; read full 16x128 cpl chunk from LDS ----
        #pragma unroll
        for (int ks2 = 0; ks2 < 4; ++ks2) {
            bf16x8 a = *(const bf16x8*)&s_cpl[row_a][(ks2 * 4 + kg) * 8];
            #pragma unroll
            for (int dt = 0; dt < 2; ++dt) {
                int d = w * 32 + dt * 16 + row_a;
                bf16x8 bb = Vv[(size_t)d * (NN / 8) + jc * 16 + ks2 * 4 + kg];
                pacc[dt] = __builtin_amdgcn_mfma_f32_16x16x32_bf16(a, bb, pacc[dt], 0, 0, 0);
            }
        }
        __syncthreads();   // before next chunk overwrites s_cpl
    }

    // ---- rowsum: reduce 16 row_a-lanes, combine 4 waves via LDS ----
    #pragma unroll
    for (int q = 0; q < 4; ++q) {
        float v = rs[q];
        v += __shfl_xor(v, 1);
        v += __shfl_xor(v, 2);
        v += __shfl_xor(v, 4);
        v += __shfl_xor(v, 8);
        if (row_a == 0) s_rs[kg * 4 + q][w] = v;
    }
    __syncthreads();

    #pragma unroll
    for (int q = 0; q < 4; ++q) {
        const int i = i0 + kg * 4 + q;
        float rsum = s_rs[kg * 4 + q][0] + s_rs[kg * 4 + q][1]
                   + s_rs[kg * 4 + q][2] + s_rs[kg * 4 + q][3];
        float inv = 1.0f / (rsum + 1e-8f);
        #pragma unroll
        for (int dt = 0; dt < 2; ++dt) {
            int d = w * 32 + dt * 16 + row_a;
            field[((size_t)b * NN + i) * DD + d] = pacc[dt][q] * inv;
        }
    }
}

// ---------------- launch ----------------
extern "C" void kernel_launch(void* const* d_in, const int* in_sizes, int n_in,
                              void* d_out, int out_size, void* d_ws, size_t ws_size,
                              hipStream_t stream) {
    const float* states = (const float*)d_in[0];
    const float* gates  = (const float*)d_in[1];
    const float* r_acc  = (const float*)d_in[2];
    const float* W_in   = (const float*)d_in[3];
    const float* W_out  = (const float*)d_in[4];
    const float* cond   = (const float*)d_in[5];

    float* field = (float*)d_out;                 // (2,1024,128)
    float* r_out = field + 2 * NN * DD;           // (2,1024,1024)

    char* ws = (char*)d_ws;
    __hip_bfloat16* M_bf = (__hip_bfloat16*)ws;                   // 512 KB @ 0
    __hip_bfloat16* valT = (__hip_bfloat16*)(ws + (512 << 10));   // 512 KB @ 512K

    hipLaunchKernelGGL(prep_kernel, dim3(128), dim3(256), 0, stream,
                       states, gates, W_in, W_out, M_bf, valT);
    hipLaunchKernelGGL(fused_kernel, dim3(128), dim3(256), 0, stream,
                       M_bf, valT, r_acc, gates, cond, r_out, field);
}

// Round 6
// 97.728 us; speedup vs baseline: 1.2177x; 1.2177x over previous
//
#include <hip/hip_runtime.h>
#include <hip/hip_bf16.h>

using bf16x8 = __attribute__((ext_vector_type(8))) short;   // 8 bf16 (16 B)
using f32x4  = __attribute__((ext_vector_type(4))) float;   // MFMA C/D frag

#define NN 1024
#define DD 128

__device__ __forceinline__ short bf16b(float f) {
    __hip_bfloat16 t = __float2bfloat16(f);
    return *(short*)&t;
}

__device__ __forceinline__ bf16x8 cvt8(const float* __restrict__ p) {
    float4 a = *(const float4*)p;
    float4 b = *(const float4*)(p + 4);
    bf16x8 r;
    r[0] = bf16b(a.x); r[1] = bf16b(a.y); r[2] = bf16b(a.z); r[3] = bf16b(a.w);
    r[4] = bf16b(b.x); r[5] = bf16b(b.y); r[6] = bf16b(b.z); r[7] = bf16b(b.w);
    return r;
}

// ---- kernel 1 (MFMA): h=S@Win^T -> M(bf16); valT=((S@Wout^T)*g)^T (bf16) ----
// grid 128 blocks (64 row-tiles x 2 batches), 4 waves.
__global__ __launch_bounds__(256) void prep_kernel(
    const float* __restrict__ states, const float* __restrict__ gates,
    const float* __restrict__ W_in, const float* __restrict__ W_out,
    __hip_bfloat16* __restrict__ M_bf, __hip_bfloat16* __restrict__ valT)
{
    __shared__ __align__(16) short s_m[16][136];    // [n_loc][d]
    __shared__ __align__(16) short s_vT[128][24];   // [d][n_loc]

    const int tid = threadIdx.x;
    const int l = tid & 63, w = tid >> 6;
    const int row_a = l & 15, kg = l >> 4;
    const int b  = blockIdx.x >> 6;
    const int n0 = (blockIdx.x & 63) * 16;
    const int colbase = w * 32;

    const float* A = states + ((size_t)b * NN + n0) * DD;

    f32x4 accH[2], accV[2];
    #pragma unroll
    for (int cp = 0; cp < 2; ++cp) {
        accH[cp] = (f32x4){0.f, 0.f, 0.f, 0.f};
        accV[cp] = (f32x4){0.f, 0.f, 0.f, 0.f};
    }

    #pragma unroll
    for (int ks = 0; ks < 4; ++ks) {
        int koff = (ks * 4 + kg) * 8;
        bf16x8 a = cvt8(A + row_a * DD + koff);
        #pragma unroll
        for (int cp = 0; cp < 2; ++cp) {
            int d = colbase + cp * 16 + row_a;
            bf16x8 b1 = cvt8(W_in  + d * DD + koff);
            bf16x8 b2 = cvt8(W_out + d * DD + koff);
            accH[cp] = __builtin_amdgcn_mfma_f32_16x16x32_bf16(a, b1, accH[cp], 0, 0, 0);
            accV[cp] = __builtin_amdgcn_mfma_f32_16x16x32_bf16(a, b2, accV[cp], 0, 0, 0);
        }
    }

    float g[4];
    #pragma unroll
    for (int q = 0; q < 4; ++q) g[q] = gates[b * NN + n0 + kg * 4 + q];

    const bool odd = (row_a & 1) != 0;
    #pragma unroll
    for (int cp = 0; cp < 2; ++cp) {
        #pragma unroll
        for (int q = 0; q < 4; ++q) {
            float hm = accH[cp][q] + 1e-8f;       // my (h+eps); col parity = lane parity
            float hp = __shfl_xor(hm, 1);         // pair partner (adjacent col/lane)
            float x = odd ? hp : hm;
            float y = odd ? hm : hp;
            float r2 = x * x + y * y;
            float out;
            if (r2 > 0.f) out = (odd ? y : x) * rsqrtf(r2);
            else          out = odd ? 0.f : 1.f;  // atan2(0,0)=0 -> cos=1,sin=0
            s_m[kg * 4 + q][colbase + cp * 16 + row_a] = bf16b(out);
            s_vT[colbase + cp * 16 + row_a][kg * 4 + q] = bf16b(accV[cp][q] * g[q]);
        }
    }
    __syncthreads();

    {   // M rows: 16B packed stores
        int r = tid >> 4, seg = tid & 15;
        bf16x8 v = *(const bf16x8*)&s_m[r][seg * 8];
        *(bf16x8*)(M_bf + ((size_t)b * NN + n0 + r) * DD + seg * 8) = v;
    }
    {   // valT[d][n0..n0+15]: 16B packed stores
        int d = tid >> 1, half = tid & 1;
        bf16x8 v = *(const bf16x8*)&s_vT[d][half * 8];
        *(bf16x8*)(valT + ((size_t)b * DD + d) * NN + n0 + half * 8) = v;
    }
}

// ---- kernel 2 (fused, flat): one 16i x 128j tile per block, no j-loop ----
// grid (8 jq, 64 it, 2 b) = 1024 blocks (4 blocks/CU, 16 waves/CU), 4 waves.
// S=M@M^T/64 -> r_out; coupling -> LDS -> PV -> bf16 field partial + rowsum partial.
__global__ __launch_bounds__(256) void fused_kernel(
    const __hip_bfloat16* __restrict__ M_bf,
    const __hip_bfloat16* __restrict__ valT,
    const float* __restrict__ r_acc,
    const float* __restrict__ gates,
    const float* __restrict__ cond_ptr,
    float* __restrict__ r_out,
    __hip_bfloat16* __restrict__ part,
    float* __restrict__ part_rs)
{
    __shared__ __align__(16) short s_cpl[16][136];   // [i_loc][j_loc]
    __shared__ float s_rs[16][4];                    // [i_loc][wave]

    const int tid = threadIdx.x;
    const int l = tid & 63, w = tid >> 6;
    const int row_a = l & 15, kg = l >> 4;
    const int jq = blockIdx.x;
    const int j0 = jq * 128;
    const int i0 = blockIdx.y * 16;
    const int b  = blockIdx.z;

    const bf16x8* Mv = (const bf16x8*)(M_bf + (size_t)b * NN * DD);
    const bf16x8* Vv = (const bf16x8*)(valT + (size_t)b * DD * NN);

    // ---- S phase: wave w covers j_local = w*32 + cp*16 + row_a ----
    f32x4 acc[2];
    acc[0] = (f32x4){0.f, 0.f, 0.f, 0.f};
    acc[1] = (f32x4){0.f, 0.f, 0.f, 0.f};
    #pragma unroll
    for (int ks = 0; ks < 4; ++ks) {
        bf16x8 a = Mv[(size_t)(i0 + row_a) * 16 + ks * 4 + kg];
        #pragma unroll
        for (int cp = 0; cp < 2; ++cp) {
            bf16x8 bb = Mv[(size_t)(j0 + w * 32 + cp * 16 + row_a) * 16 + ks * 4 + kg];
            acc[cp] = __builtin_amdgcn_mfma_f32_16x16x32_bf16(a, bb, acc[cp], 0, 0, 0);
        }
    }

    const float cond = fminf(fmaxf(cond_ptr[0], -5.f), 5.f);
    float g_i[4], g_j[2];
    #pragma unroll
    for (int q = 0; q < 4; ++q) g_i[q] = gates[(size_t)b * NN + i0 + kg * 4 + q];
    #pragma unroll
    for (int cp = 0; cp < 2; ++cp) g_j[cp] = gates[(size_t)b * NN + j0 + w * 32 + cp * 16 + row_a];

    const size_t robase = (size_t)b * NN * NN;
    float rs[4] = {0.f, 0.f, 0.f, 0.f};

    #pragma unroll
    for (int q = 0; q < 4; ++q) {
        const int i = i0 + kg * 4 + q;               // C/D row = kg*4+q [m89]
        const float gi = g_i[q];
        #pragma unroll
        for (int cp = 0; cp < 2; ++cp) {
            const int jl = w * 32 + cp * 16 + row_a;
            const int j  = j0 + jl;                  // C/D col = lane&15
            float s  = acc[cp][q] * (1.f / 64.f);
            float ra = r_acc[robase + (size_t)i * NN + j];
            float rn = fminf(fmaxf(0.7f * ra + 0.3f * s, -2.f), 2.f);
            r_out[robase + (size_t)i * NN + j] = rn;
            float cpl = (i == j) ? 0.f
                        : (1.f / (1.f + __expf(-cond * rn))) * gi * g_j[cp];
            rs[q] += cpl;
            s_cpl[kg * 4 + q][jl] = bf16b(cpl);
        }
    }

    // rowsum partials: reduce over the 16 row_a lanes
    #pragma unroll
    for (int q = 0; q < 4; ++q) {
        float v = rs[q];
        v += __shfl_xor(v, 1);
        v += __shfl_xor(v, 2);
        v += __shfl_xor(v, 4);
        v += __shfl_xor(v, 8);
        if (row_a == 0) s_rs[kg * 4 + q][w] = v;
    }
    __syncthreads();

    // ---- PV: wave w owns d-quarter w*32..+31; full 16x128 cpl chunk from LDS ----
    f32x4 pacc[2];
    pacc[0] = (f32x4){0.f, 0.f, 0.f, 0.f};
    pacc[1] = (f32x4){0.f, 0.f, 0.f, 0.f};
    #pragma unroll
    for (int ks2 = 0; ks2 < 4; ++ks2) {
        bf16x8 a = *(const bf16x8*)&s_cpl[row_a][(ks2 * 4 + kg) * 8];
        #pragma unroll
        for (int dt = 0; dt < 2; ++dt) {
            int d = w * 32 + dt * 16 + row_a;
            bf16x8 bb = Vv[(size_t)d * (NN / 8) + (j0 >> 3) + ks2 * 4 + kg];
            pacc[dt] = __builtin_amdgcn_mfma_f32_16x16x32_bf16(a, bb, pacc[dt], 0, 0, 0);
        }
    }

    __hip_bfloat16* pb = part + ((size_t)jq * 2 + b) * NN * DD;
    #pragma unroll
    for (int dt = 0; dt < 2; ++dt) {
        #pragma unroll
        for (int q = 0; q < 4; ++q) {
            int i = i0 + kg * 4 + q;
            int d = w * 32 + dt * 16 + row_a;
            pb[(size_t)i * DD + d] = __float2bfloat16(pacc[dt][q]);
        }
    }

    if (tid < 16)
        part_rs[((size_t)jq * 2 + b) * NN + i0 + tid] =
            s_rs[tid][0] + s_rs[tid][1] + s_rs[tid][2] + s_rs[tid][3];
}

// ---- kernel 3: field = (sum_jq part[jq]) / (sum_jq rs[jq] + 1e-8) ----
__global__ __launch_bounds__(256) void reduce_kernel(
    const __hip_bfloat16* __restrict__ part,
    const float* __restrict__ part_rs,
    float* __restrict__ field)
{
    int t   = blockIdx.x * 256 + threadIdx.x;   // 65536 total
    int b   = t >> 15;
    int rem = t & 32767;
    int i   = rem >> 5;
    int d4  = (rem & 31) * 4;
    size_t ibase = (size_t)i * DD + d4;

    float s0 = 0.f, s1 = 0.f, s2 = 0.f, s3 = 0.f, rsum = 0.f;
    #pragma unroll
    for (int jq = 0; jq < 8; ++jq) {
        size_t slab = ((size_t)jq * 2 + b);
        uint2 u = *(const uint2*)(part + slab * NN * DD + ibase);
        s0 += __uint_as_float(u.x << 16);
        s1 += __uint_as_float(u.x & 0xffff0000u);
        s2 += __uint_as_float(u.y << 16);
        s3 += __uint_as_float(u.y & 0xffff0000u);
        rsum += part_rs[slab * NN + i];
    }
    float inv = 1.0f / (rsum + 1e-8f);
    float4 o = {s0 * inv, s1 * inv, s2 * inv, s3 * inv};
    *(float4*)(field + ((size_t)b * NN + i) * DD + d4) = o;
}

// ---------------- launch ----------------
extern "C" void kernel_launch(void* const* d_in, const int* in_sizes, int n_in,
                              void* d_out, int out_size, void* d_ws, size_t ws_size,
                              hipStream_t stream) {
    const float* states = (const float*)d_in[0];
    const float* gates  = (const float*)d_in[1];
    const float* r_acc  = (const float*)d_in[2];
    const float* W_in   = (const float*)d_in[3];
    const float* W_out  = (const float*)d_in[4];
    const float* cond   = (const float*)d_in[5];

    float* field = (float*)d_out;                 // (2,1024,128)
    float* r_out = field + 2 * NN * DD;           // (2,1024,1024)

    char* ws = (char*)d_ws;
    __hip_bfloat16* M_bf    = (__hip_bfloat16*)ws;                   // 512 KB @ 0
    __hip_bfloat16* valT    = (__hip_bfloat16*)(ws + (512 << 10));   // 512 KB @ 512K
    __hip_bfloat16* part    = (__hip_bfloat16*)(ws + (1 << 20));     // 4 MB  @ 1M
    float*          part_rs = (float*)(ws + (5 << 20));              // 64 KB @ 5M

    hipLaunchKernelGGL(prep_kernel, dim3(128), dim3(256), 0, stream,
                       states, gates, W_in, W_out, M_bf, valT);
    hipLaunchKernelGGL(fused_kernel, dim3(8, 64, 2), dim3(256), 0, stream,
                       M_bf, valT, r_acc, gates, cond, r_out, part, part_rs);
    hipLaunchKernelGGL(reduce_kernel, dim3(256), dim3(256), 0, stream,
                       part, part_rs, field);
}